// Round 22
// baseline (41.410 us; speedup 1.0000x reference)
//
#include <hip/hip_runtime.h>
#include <math.h>

namespace {

constexpr int D = 256;
constexpr int H = 8;

typedef __attribute__((ext_vector_type(8))) short bf16x8;
typedef __attribute__((ext_vector_type(4))) float f32x4;

__device__ inline unsigned short bf16rn(float x) {
  unsigned u = __builtin_bit_cast(unsigned, x);
  u += 0x7fffu + ((u >> 16) & 1u);
  return (unsigned short)(u >> 16);
}
__device__ inline float bf16tof(unsigned short b) {
  return __builtin_bit_cast(float, (unsigned)b << 16);
}
// split a f32 octet into hi/lo bf16x8 (identical values to prep's hi/lo path)
__device__ inline void hilo8(const float* e, bf16x8& hv, bf16x8& lv) {
  #pragma unroll
  for (int p = 0; p < 8; ++p) {
    unsigned short h = bf16rn(e[p]);
    hv[p] = (short)h;
    lv[p] = (short)bf16rn(e[p] - bf16tof(h));
  }
}

// ---------------- Kernel 1: qW direct (prep+qw merged) -> bf16 qW ----------------
// Grid 1024 x 256 thr = 4096 waves (16 waves/CU). Wave w: bn-tile bt = w>>6,
// he-pair hp = w&63 (he tiles hp*2, hp*2+1). Per ks: gather A-frags from q and
// B-frags from W DIRECTLY (prep's verified formulas, L2-hot: q 1MB, W 2MB),
// hi/lo split in-register, 3-MFMA accumulate (bit-identical to the R11-R21
// prep->qw_mfma pipeline). Output bf16 row-major [bn][2048] (R21 format).
__global__ __launch_bounds__(256) void qw_direct_kernel(
    const float* __restrict__ q, const float* __restrict__ W,
    unsigned short* __restrict__ qWb) {
  const int tid = threadIdx.x;
  const int w   = blockIdx.x * 4 + (tid >> 6);
  const int l   = tid & 63;
  const int bt  = w >> 6;            // bn-tile 0..63
  const int hp  = w & 63;            // he-pair 0..63
  const int lrow  = l & 15;
  const int lcol8 = (l >> 4) << 3;

  f32x4 acc[2];
  acc[0] = f32x4{0.f, 0.f, 0.f, 0.f};
  acc[1] = f32x4{0.f, 0.f, 0.f, 0.f};

  const float* qbase = q + (size_t)(bt * 16 + lrow) * 256 + lcol8;

  #pragma unroll 2
  for (int ks = 0; ks < 8; ++ks) {
    // ---- A-frag: q row, 8 consecutive f32 (prep q-part formula)
    float ea[8];
    {
      const float4 a0 = *reinterpret_cast<const float4*>(qbase + ks * 32);
      const float4 a1 = *reinterpret_cast<const float4*>(qbase + ks * 32 + 4);
      ea[0] = a0.x; ea[1] = a0.y; ea[2] = a0.z; ea[3] = a0.w;
      ea[4] = a1.x; ea[5] = a1.y; ea[6] = a1.z; ea[7] = a1.w;
    }
    bf16x8 aH, aL;
    hilo8(ea, aH, aL);

    // ---- B-frags: 2 he-tiles, 8 column-strided f32 each (prep W-part formula)
    #pragma unroll
    for (int j = 0; j < 2; ++j) {
      const int he = hp * 2 + j;
      const int h  = he >> 4, et = he & 15;
      const float* wp = W + (size_t)h * 65536 +
                        (size_t)(ks * 32 + lcol8) * 256 + et * 16 + lrow;
      float eb[8];
      #pragma unroll
      for (int jj = 0; jj < 8; ++jj) eb[jj] = wp[(size_t)jj * 256];
      bf16x8 bH, bL;
      hilo8(eb, bH, bL);
      acc[j] = __builtin_amdgcn_mfma_f32_16x16x32_bf16(aH, bH, acc[j], 0, 0, 0);
      acc[j] = __builtin_amdgcn_mfma_f32_16x16x32_bf16(aH, bL, acc[j], 0, 0, 0);
      acc[j] = __builtin_amdgcn_mfma_f32_16x16x32_bf16(aL, bH, acc[j], 0, 0, 0);
    }
  }

  // ---- bf16 output (R21-verified C layout: row=(l>>4)*4+r (bn), col=l&15 (he))
  const int rbase = (l >> 4) * 4;
  const int col   = l & 15;
  #pragma unroll
  for (int j = 0; j < 2; ++j) {
    const size_t cidx = (size_t)(hp * 2 + j) * 16 + col;
    #pragma unroll
    for (int r = 0; r < 4; ++r) {
      const int bn = bt * 16 + rbase + r;
      qWb[(size_t)bn * 2048 + cidx] = bf16rn(acc[j][r]);
    }
  }
}

// ---------------- Kernel 2: fused scores+softmax+PV (byte-identical to R21) ------
constexpr int FB2   = 0;
constexpr int WSP2  = 8320;
constexpr int SMEM3 = 9344;

__global__ __launch_bounds__(256, 4) void attn_fused_kernel(
    const unsigned short* __restrict__ qWb, const float* __restrict__ kin,
    const float* __restrict__ vin, const float* __restrict__ bin,
    float* __restrict__ out, float* __restrict__ attn_out) {
  __shared__ alignas(16) long long smem_ll[SMEM3 / 8];
  char* sm = reinterpret_cast<char*>(smem_ll);
  float* wsp = reinterpret_cast<float*>(sm + WSP2);   // flat [4*64]
  const int tid = threadIdx.x;
  const int bn  = blockIdx.x;
  const int wid = tid >> 6;
  const int ln  = tid & 63;

  // ---- A-direct k-frag loads (16 independent float4; R14-verified addressing)
  const float* arow = kin + (size_t)bn * 16384 +
                      (size_t)(wid * 16 + (ln & 15)) * 256 + ((ln >> 4) << 3);
  float4 ka[16];
  #pragma unroll
  for (int ks = 0; ks < 8; ++ks) {
    ka[2 * ks]     = *reinterpret_cast<const float4*>(arow + ks * 32);
    ka[2 * ks + 1] = *reinterpret_cast<const float4*>(arow + ks * 32 + 4);
  }
  // ---- qW bf16 load: 8 bf16/thread
  uint4 qh = *reinterpret_cast<const uint4*>(qWb + (size_t)bn * 2048 + tid * 8);

  // ---- zero-fill unwritten B slots (cols 8-15)
  {
    const int ks = tid >> 5, slot = 32 + (tid & 31);
    *reinterpret_cast<uint4*>(sm + FB2 + ks * 1040 + slot * 16) =
        make_uint4(0u, 0u, 0u, 0u);
  }
  // ---- B-hi frag placement (verified formulas); p = 2*tid, 2*tid+1
  #pragma unroll
  for (int i = 0; i < 2; ++i) {
    const int p = 2 * tid + i;
    const int hh = p >> 6, equad = p & 63;
    const int ks = equad >> 3, g = (equad >> 1) & 3, j0 = (equad & 1) * 4;
    const int base = FB2 + ks * 1040 + (hh * 4 + g) * 16 + j0 * 2;
    *reinterpret_cast<uint2*>(sm + base) =
        i == 0 ? make_uint2(qh.x, qh.y) : make_uint2(qh.z, qh.w);
  }
  __syncthreads();

  // ---- MFMA over full K=256, tile T = wid (converts ka in registers)
  const int slot_r = (ln & 15) * 4 + (ln >> 4);
  const char* pbH = sm + FB2 + slot_r * 16;
  f32x4 acc = {0.f, 0.f, 0.f, 0.f};
  #pragma unroll
  for (int ks = 0; ks < 8; ++ks) {
    const float4 a0 = ka[2 * ks], a1 = ka[2 * ks + 1];
    bf16x8 aH;
    aH[0] = (short)bf16rn(a0.x); aH[1] = (short)bf16rn(a0.y);
    aH[2] = (short)bf16rn(a0.z); aH[3] = (short)bf16rn(a0.w);
    aH[4] = (short)bf16rn(a1.x); aH[5] = (short)bf16rn(a1.y);
    aH[6] = (short)bf16rn(a1.z); aH[7] = (short)bf16rn(a1.w);
    bf16x8 bH = *reinterpret_cast<const bf16x8*>(pbH + ks * 1040);
    acc = __builtin_amdgcn_mfma_f32_16x16x32_bf16(aH, bH, acc, 0, 0, 0);
  }

  // ---- softmax on C-frags (R14-verified reduce)
  const float bias = bin[ln & 7];
  const int col = ln & 15;
  const bool valid = col < 8;
  float x0 = acc[0] + bias, x1 = acc[1] + bias, x2 = acc[2] + bias, x3 = acc[3] + bias;
  float m = valid ? fmaxf(fmaxf(x0, x1), fmaxf(x2, x3)) : -1e30f;
  m = fmaxf(m, __shfl_xor(m, 1, 64));
  m = fmaxf(m, __shfl_xor(m, 2, 64));
  m = fmaxf(m, __shfl_xor(m, 4, 64));
  m = fmaxf(m, __shfl_xor(m, 16, 64));
  float e0 = valid ? expf(x0 - m) : 0.f;
  float e1 = valid ? expf(x1 - m) : 0.f;
  float e2 = valid ? expf(x2 - m) : 0.f;
  float e3 = valid ? expf(x3 - m) : 0.f;
  float s = e0 + e1 + e2 + e3;
  s += __shfl_xor(s, 1, 64);
  s += __shfl_xor(s, 2, 64);
  s += __shfl_xor(s, 4, 64);
  s += __shfl_xor(s, 16, 64);
  float inv = 1.f / s;
  float p0 = e0 * inv, p1 = e1 * inv, p2 = e2 * inv, p3 = e3 * inv;
  if (valid) {
    size_t base = (size_t)bn * 512 + (size_t)(wid * 16 + (ln >> 4) * 4) * 8 + col;
    attn_out[base]      = p0;
    attn_out[base + 8]  = p1;
    attn_out[base + 16] = p2;
    attn_out[base + 24] = p3;
  }
  // wsum partial: pos=(row&7)*8+col, chunk-pair sum via xor-32; one writer/pos.
  p0 += __shfl_xor(p0, 32, 64);
  p1 += __shfl_xor(p1, 32, 64);
  p2 += __shfl_xor(p2, 32, 64);
  p3 += __shfl_xor(p3, 32, 64);
  if (ln < 32 && (ln & 15) < 8) {
    const int rb = (ln >> 4) * 4;
    const int c8 = ln & 7;
    float* w = wsp + wid * 64;
    w[(rb + 0) * 8 + c8] = p0;
    w[(rb + 1) * 8 + c8] = p1;
    w[(rb + 2) * 8 + c8] = p2;
    w[(rb + 3) * 8 + c8] = p3;
  }
  __syncthreads();

  // ---- PV: 16 independent coalesced v loads; wsum via broadcast LDS reads
  const float4* v4 = reinterpret_cast<const float4*>(vin) + (size_t)bn * 4096;
  float4 av = make_float4(0.f, 0.f, 0.f, 0.f);
  #pragma unroll
  for (int i = 0; i < 16; ++i) {
    const int r = wid + 4 * i;
    float w = wsp[r] + wsp[64 + r] + wsp[128 + r] + wsp[192 + r];
    float4 vv = v4[r * 64 + ln];
    av.x += w * vv.x; av.y += w * vv.y; av.z += w * vv.z; av.w += w * vv.w;
  }
  float* s_red = reinterpret_cast<float*>(sm);   // [4][260] alias on dead B-frag area
  *reinterpret_cast<float4*>(&s_red[wid * 260 + (ln << 2)]) = av;
  __syncthreads();

  out[(size_t)bn * D + tid] =
      s_red[tid] + s_red[260 + tid] + s_red[520 + tid] + s_red[780 + tid];
}

}  // namespace

extern "C" void kernel_launch(void* const* d_in, const int* in_sizes, int n_in,
                              void* d_out, int out_size, void* d_ws, size_t ws_size,
                              hipStream_t stream) {
  const float* q = (const float*)d_in[0];   // (8,128,1,256)
  const float* k = (const float*)d_in[1];   // (8,128,64,256)
  const float* v = (const float*)d_in[2];   // (8,128,64,256)
  const float* W = (const float*)d_in[3];   // (8,256,256)
  const float* b = (const float*)d_in[4];   // (8,)

  float* out  = (float*)d_out;              // output: 262144 f32
  float* attn = out + 262144;               // attn:   524288 f32
  unsigned short* qWb = (unsigned short*)d_ws;  // 2 MiB bf16 qW [bn][2048]

  hipLaunchKernelGGL(qw_direct_kernel,  dim3(1024), dim3(256), 0, stream, q, W, qWb);
  hipLaunchKernelGGL(attn_fused_kernel, dim3(1024), dim3(256), 0, stream,
                     qWb, k, v, b, out, attn);
}